// Round 1
// baseline (589.807 us; speedup 1.0000x reference)
//
#include <hip/hip_runtime.h>
#include <math.h>

// GASLayer: per-column EMA normalization with chunked parallel scan.
// T=32768 rows, D=1024 cols. C=128 chunks of L=256 rows.
// ws layout (floats, n = C*D = 131072 each):
//   [0] sum, [1] sumsq, [2] B_mu, [3] Q0, [4] Q1, [5] Q2, [6] mu_in, [7] var_in
// Total ws use: 8 * 131072 * 4 B = 4 MiB.

#define T_DIM 32768
#define D_DIM 1024
#define CHUNK 128
#define CLEN  (T_DIM / CHUNK)   // 256
#define ETA_MU_F 0.01f
#define ETA_VAR_F 0.02f

// K1: per-(chunk, column) summaries. One thread per (c,d).
// mu_k = a^{k+1} * mu_in + m_k  (m = zero-init run), p_k = a^{k+1}
// var_out = b^L var_in + Q0 + Q1*mu_in + Q2*mu_in^2
__global__ __launch_bounds__(256) void k_chunk_summary(
    const float* __restrict__ x, float* __restrict__ ws) {
    const int g = blockIdx.x * 256 + threadIdx.x;   // [0, C*D)
    const int d = g & (D_DIM - 1);
    const int c = g >> 10;
    const float a = 1.0f - ETA_MU_F;
    const float b = 1.0f - ETA_VAR_F;

    float s = 0.0f, s2 = 0.0f;
    float m = 0.0f;                 // mu with mu_in = 0
    float q0 = 0.0f, q1 = 0.0f, q2 = 0.0f;
    float p = 1.0f;                 // becomes a^{k+1} after update below

    const float* xp = x + (size_t)c * CLEN * D_DIM + d;
#pragma unroll 4
    for (int k = 0; k < CLEN; ++k) {
        float xv = xp[(size_t)k * D_DIM];
        s  += xv;
        s2 += xv * xv;
        m = m + ETA_MU_F * (xv - m);     // same arithmetic form as replay
        p *= a;                           // p = a^{k+1}
        float dv = xv - m;
        q0 = b * q0 + ETA_VAR_F * dv * dv;
        q1 = b * q1 - 2.0f * ETA_VAR_F * dv * p;
        q2 = b * q2 + ETA_VAR_F * p * p;
    }
    const int n = CHUNK * D_DIM;
    ws[0 * n + g] = s;
    ws[1 * n + g] = s2;
    ws[2 * n + g] = m;
    ws[3 * n + g] = q0;
    ws[4 * n + g] = q1;
    ws[5 * n + g] = q2;
}

// K2: per-column. Reduce partials -> mu0, std0 (reference stores STD in the
// var slot initially), then scan the C chunk summaries to get entry states.
__global__ __launch_bounds__(256) void k_scan(
    float* __restrict__ ws, float a_pow, float b_pow) {
    const int d = blockIdx.x * 256 + threadIdx.x;   // [0, D)
    const int n = CHUNK * D_DIM;
    const float* sum  = ws + 0 * n;
    const float* sum2 = ws + 1 * n;
    const float* bmu  = ws + 2 * n;
    const float* q0   = ws + 3 * n;
    const float* q1   = ws + 4 * n;
    const float* q2   = ws + 5 * n;
    float* mu_in  = ws + 6 * n;
    float* var_in = ws + 7 * n;

    float s = 0.0f, s2 = 0.0f;
#pragma unroll 8
    for (int c = 0; c < CHUNK; ++c) {
        s  += sum[c * D_DIM + d];
        s2 += sum2[c * D_DIM + d];
    }
    float mu0 = s / (float)T_DIM;
    float v0  = (s2 - (float)T_DIM * mu0 * mu0) / (float)(T_DIM - 1);
    float std0 = sqrtf(fmaxf(v0, 0.0f));

    float mu = mu0;
    float var = std0;   // NOTE: std, not variance — matches reference
#pragma unroll 4
    for (int c = 0; c < CHUNK; ++c) {
        int idx = c * D_DIM + d;
        mu_in[idx]  = mu;
        var_in[idx] = var;
        float mu_next = a_pow * mu + bmu[idx];
        var = b_pow * var + q0[idx] + mu * (q1[idx] + q2[idx] * mu);
        mu = mu_next;
    }
}

// K3: replay each chunk with exact reference arithmetic, write outputs.
__global__ __launch_bounds__(256) void k_replay(
    const float* __restrict__ x, const float* __restrict__ ws,
    float* __restrict__ out) {
    const int g = blockIdx.x * 256 + threadIdx.x;   // [0, C*D)
    const int d = g & (D_DIM - 1);
    const int c = g >> 10;
    const int n = CHUNK * D_DIM;

    float mu  = ws[6 * n + g];
    float var = ws[7 * n + g];

    const size_t t0 = (size_t)c * CLEN;
    const float* xp = x + t0 * D_DIM + d;
    float* norm_out = out + t0 * D_DIM + d;
    float* info = out + (size_t)T_DIM * D_DIM + t0 * (2 * D_DIM) + d;

#pragma unroll 4
    for (int k = 0; k < CLEN; ++k) {
        float xv = xp[(size_t)k * D_DIM];
        mu = mu + ETA_MU_F * (xv - mu);
        float diff = xv - mu;
        var = (1.0f - ETA_VAR_F) * var + ETA_VAR_F * diff * diff;
        norm_out[(size_t)k * D_DIM] = diff / sqrtf(var);
        info[(size_t)k * (2 * D_DIM)]         = mu;
        info[(size_t)k * (2 * D_DIM) + D_DIM] = var;
    }
}

extern "C" void kernel_launch(void* const* d_in, const int* in_sizes, int n_in,
                              void* d_out, int out_size, void* d_ws, size_t ws_size,
                              hipStream_t stream) {
    const float* x = (const float*)d_in[0];
    float* out = (float*)d_out;
    float* ws = (float*)d_ws;

    // Constant decay-over-chunk factors, computed in double on host.
    float a_pow = (float)pow(1.0 - 0.01, (double)CLEN);  // 0.99^256
    float b_pow = (float)pow(1.0 - 0.02, (double)CLEN);  // 0.98^256

    const int n = CHUNK * D_DIM;               // 131072 threads for K1/K3
    hipLaunchKernelGGL(k_chunk_summary, dim3(n / 256), dim3(256), 0, stream, x, ws);
    hipLaunchKernelGGL(k_scan, dim3(D_DIM / 256), dim3(256), 0, stream, ws, a_pow, b_pow);
    hipLaunchKernelGGL(k_replay, dim3(n / 256), dim3(256), 0, stream, x, ws, out);
}